// Round 4
// baseline (157.330 us; speedup 1.0000x reference)
//
#include <hip/hip_runtime.h>
#include <math.h>

#define BB 4
#define S 8192
#define C 256
#define NW 2048
#define WS 256
#define PSZ 256
#define DD 32
#define KK 65
#define TOTW (BB * NW) /* 8192 */

// ---------------------------------------------------------------------------
// Kernel 0: transpose W_p [PSZ][WS] -> WpT [WS][PSZ]
// ---------------------------------------------------------------------------
__global__ __launch_bounds__(256) void wp_transpose(const float* __restrict__ Wp,
                                                    float* __restrict__ WpT) {
    int p = blockIdx.x;
    int ws = threadIdx.x;
    WpT[ws * PSZ + p] = Wp[p * WS + ws];
}

// ---------------------------------------------------------------------------
// Kernel 1: per-window precompute, v3.
//   g[w][c] = sum_ws c_t[w][ws] * W_a[ws][c]
//   p_t[w]  = S * sigmoid( sum_p tanh(c_t @ W_p^T)[p] * V_p[p] )
// R3 lesson: 512 blocks x 256 thr was GRID-limited to 2 waves/SIMD; neither
// the compiler nor manual prefetch can hide L2/LDS latency with so few waves.
// v3: 512 blocks x 1024 thr (16 waves) -> 2 blocks/CU = 32 waves/CU = FULL
// occupancy. tid=(tm 0..3, tn 0..255): thread owns 4 windows x (h,g) cols ->
// 8 accums (~45 VGPR, __launch_bounds__(1024,8) pins 8 waves/SIMD).
// c_t read as wave-uniform global float4 loads (16 KB block -> L1-resident
// broadcast); no LDS staging, no prefetch — TLP hides everything.
// Weight L2 traffic stays 512 blk x 512 KB = 256 MB (~7.4 us, overlapped).
// ---------------------------------------------------------------------------
__global__ __launch_bounds__(1024, 8) void precomp(const float* __restrict__ ct,
                                                   const float* __restrict__ WpT,
                                                   const float* __restrict__ Wa,
                                                   const float* __restrict__ Vp,
                                                   float* __restrict__ g,
                                                   float* __restrict__ pt) {
    __shared__ float red[16][4];

    const int tid = threadIdx.x;
    const int tn = tid & 255;          // output column (h[tn], g[tn])
    const int tm = tid >> 8;           // window group 0..3
    const int lane = tid & 63;
    const int w4 = (tid >> 6) & 3;     // wave within tm group
    const int wbase = blockIdx.x * 16;
    const int w0 = wbase + tm * 4;

    const float* ctb = ct + (size_t)w0 * WS;

    float hacc[4] = {0.f, 0.f, 0.f, 0.f};
    float gacc[4] = {0.f, 0.f, 0.f, 0.f};

    for (int k = 0; k < WS; k += 4) {
        const float wp0 = WpT[(k + 0) * PSZ + tn];
        const float wp1 = WpT[(k + 1) * PSZ + tn];
        const float wp2 = WpT[(k + 2) * PSZ + tn];
        const float wp3 = WpT[(k + 3) * PSZ + tn];
        const float wa0 = Wa[(k + 0) * C + tn];
        const float wa1 = Wa[(k + 1) * C + tn];
        const float wa2 = Wa[(k + 2) * C + tn];
        const float wa3 = Wa[(k + 3) * C + tn];
#pragma unroll
        for (int r = 0; r < 4; r++) {
            const float4 c4 = *(const float4*)(ctb + (size_t)r * WS + k); // wave-uniform
            hacc[r] = fmaf(c4.x, wp0, hacc[r]);
            hacc[r] = fmaf(c4.y, wp1, hacc[r]);
            hacc[r] = fmaf(c4.z, wp2, hacc[r]);
            hacc[r] = fmaf(c4.w, wp3, hacc[r]);
            gacc[r] = fmaf(c4.x, wa0, gacc[r]);
            gacc[r] = fmaf(c4.y, wa1, gacc[r]);
            gacc[r] = fmaf(c4.z, wa2, gacc[r]);
            gacc[r] = fmaf(c4.w, wa3, gacc[r]);
        }
    }

    // g rows: coalesced (256 consecutive floats per (tm,r))
#pragma unroll
    for (int r = 0; r < 4; r++) g[(size_t)(w0 + r) * C + tn] = gacc[r];

    // p_t: reduce tanh(h)*V_p over the 256 columns of each window
    const float vp = Vp[tn];
#pragma unroll
    for (int r = 0; r < 4; r++) {
        float v = tanhf(hacc[r]) * vp;
#pragma unroll
        for (int off = 32; off >= 1; off >>= 1) v += __shfl_xor(v, off);
        if (lane == 0) red[tm * 4 + r][w4] = v;
    }
    __syncthreads();
    if (tid < 16) {
        const float x = red[tid][0] + red[tid][1] + red[tid][2] + red[tid][3];
        const float sig = 1.f / (1.f + expf(-x));
        pt[wbase + tid] = (float)S * sig;
    }
}

// ---------------------------------------------------------------------------
// Kernel 2: gather-attention, one wave per window (unchanged from R2).
// ---------------------------------------------------------------------------
__global__ __launch_bounds__(256) void attn(const float* __restrict__ q,
                                            const float* __restrict__ g,
                                            const float* __restrict__ pt,
                                            float* __restrict__ out) {
    const int tid = threadIdx.x;
    const int lane = tid & 63;
    const int wv = tid >> 6;
    const int wg = (blockIdx.x << 2) | wv;     // global window
    const int b = wg >> 11;                    // NW = 2048
    const int grp = lane >> 4;                 // key sub-slot
    const int sub = lane & 15;                 // channel group

    const float p = pt[wg];
    const int s0 = (int)p;                     // trunc == floor (p > 0)

    const float* grow = g + (size_t)wg * C + sub * 4;
    const float4 g0 = *(const float4*)(grow);
    const float4 g1 = *(const float4*)(grow + 64);
    const float4 g2 = *(const float4*)(grow + 128);
    const float4 g3 = *(const float4*)(grow + 192);

    const float* qb = q + (size_t)b * S * C + sub * 4;

    float m = -1e30f, den = 0.f;
    float4 a0 = {0, 0, 0, 0}, a1 = {0, 0, 0, 0}, a2 = {0, 0, 0, 0}, a3 = {0, 0, 0, 0};

    for (int it = 0; it < 17; it++) {
        const int k = it * 4 + grp;
        const int s = s0 + k - DD;
        const bool valid = (k <= 64) && ((unsigned)s < (unsigned)S);
        const int srow = min(max(s, 0), S - 1);

        const float* qr = qb + (size_t)srow * C;
        const float4 q0 = *(const float4*)(qr);
        const float4 q1 = *(const float4*)(qr + 64);
        const float4 q2 = *(const float4*)(qr + 128);
        const float4 q3 = *(const float4*)(qr + 192);

        float d = q0.x * g0.x;
        d = fmaf(q0.y, g0.y, d); d = fmaf(q0.z, g0.z, d); d = fmaf(q0.w, g0.w, d);
        d = fmaf(q1.x, g1.x, d); d = fmaf(q1.y, g1.y, d);
        d = fmaf(q1.z, g1.z, d); d = fmaf(q1.w, g1.w, d);
        d = fmaf(q2.x, g2.x, d); d = fmaf(q2.y, g2.y, d);
        d = fmaf(q2.z, g2.z, d); d = fmaf(q2.w, g2.w, d);
        d = fmaf(q3.x, g3.x, d); d = fmaf(q3.y, g3.y, d);
        d = fmaf(q3.w, g3.w, d); d = fmaf(q3.z, g3.z, d);
#pragma unroll
        for (int off = 8; off >= 1; off >>= 1) d += __shfl_xor(d, off);

        d = valid ? d : -3e38f;

        const float fs = (float)s - p;
        const float t = fs * (1.f / (float)DD);
        const float lg = -2.f * t * t;

        const float mn = fmaxf(m, d);
        const float sc = __expf(m - mn);       // rescale old state
        const float e  = __expf(d - mn);       // denominator term
        const float eg = __expf(d - mn + lg);  // numerator term (exp * gauss)
        den = fmaf(den, sc, e);
        m = mn;

        a0.x = fmaf(eg, q0.x, a0.x * sc); a0.y = fmaf(eg, q0.y, a0.y * sc);
        a0.z = fmaf(eg, q0.z, a0.z * sc); a0.w = fmaf(eg, q0.w, a0.w * sc);
        a1.x = fmaf(eg, q1.x, a1.x * sc); a1.y = fmaf(eg, q1.y, a1.y * sc);
        a1.z = fmaf(eg, q1.z, a1.z * sc); a1.w = fmaf(eg, q1.w, a1.w * sc);
        a2.x = fmaf(eg, q2.x, a2.x * sc); a2.y = fmaf(eg, q2.y, a2.y * sc);
        a2.z = fmaf(eg, q2.z, a2.z * sc); a2.w = fmaf(eg, q2.w, a2.w * sc);
        a3.x = fmaf(eg, q3.x, a3.x * sc); a3.y = fmaf(eg, q3.y, a3.y * sc);
        a3.z = fmaf(eg, q3.z, a3.z * sc); a3.w = fmaf(eg, q3.w, a3.w * sc);
    }

    // merge the 4 groups (cross-lane butterfly; m/den uniform within group)
    float M = m;
    M = fmaxf(M, __shfl_xor(M, 16));
    M = fmaxf(M, __shfl_xor(M, 32));
    const float scg = __expf(m - M);

    den *= scg;
    den += __shfl_xor(den, 16);
    den += __shfl_xor(den, 32);

#define MERGE(v) { v *= scg; v += __shfl_xor(v, 16); v += __shfl_xor(v, 32); }
    MERGE(a0.x) MERGE(a0.y) MERGE(a0.z) MERGE(a0.w)
    MERGE(a1.x) MERGE(a1.y) MERGE(a1.z) MERGE(a1.w)
    MERGE(a2.x) MERGE(a2.y) MERGE(a2.z) MERGE(a2.w)
    MERGE(a3.x) MERGE(a3.y) MERGE(a3.z) MERGE(a3.w)
#undef MERGE

    float4 o = a0;
    if (grp == 1) o = a1;
    else if (grp == 2) o = a2;
    else if (grp == 3) o = a3;

    const float r = 1.f / den;
    o.x *= r; o.y *= r; o.z *= r; o.w *= r;

    *(float4*)(out + (size_t)wg * C + lane * 4) = o;
}

// ---------------------------------------------------------------------------
extern "C" void kernel_launch(void* const* d_in, const int* in_sizes, int n_in,
                              void* d_out, int out_size, void* d_ws, size_t ws_size,
                              hipStream_t stream) {
    const float* q  = (const float*)d_in[0];
    const float* ct = (const float*)d_in[1];
    const float* Wa = (const float*)d_in[2];
    const float* Wp = (const float*)d_in[3];
    const float* Vp = (const float*)d_in[4];
    float* out = (float*)d_out;

    char* ws = (char*)d_ws;
    float* WpT = (float*)ws;                          // 256 KB
    float* pt  = (float*)(ws + 262144);               // 32 KB
    float* g   = (float*)(ws + 262144 + 32768);       // 8 MB

    wp_transpose<<<PSZ, WS, 0, stream>>>(Wp, WpT);
    precomp<<<TOTW / 16, 1024, 0, stream>>>(ct, WpT, Wa, Vp, g, pt);
    attn<<<TOTW / 4, 256, 0, stream>>>(q, g, pt, out);
}

// Round 5
// 105.937 us; speedup vs baseline: 1.4851x; 1.4851x over previous
//
#include <hip/hip_runtime.h>
#include <math.h>

#define BB 4
#define S 8192
#define C 256
#define NW 2048
#define WS 256
#define PSZ 256
#define DD 32
#define KK 65
#define TOTW (BB * NW) /* 8192 */

#define TM 64
#define TN 64
#define KC 64
#define LDA 68  /* 64 + 4 pad, keeps 16B alignment (68*4=272=17*16) */

// ---------------------------------------------------------------------------
// Kernel 0: pack B [256 k][512 cols] = [ Wp^T | Wa ].
//   B[k][p]     = Wp[p][k]   (h columns)
//   B[k][256+c] = Wa[k][c]   (g columns)
// ---------------------------------------------------------------------------
__global__ __launch_bounds__(256) void prep_B(const float* __restrict__ Wp,
                                              const float* __restrict__ Wa,
                                              float* __restrict__ Bp) {
    const int k = blockIdx.x;
    const int t = threadIdx.x;
    Bp[k * 512 + t] = Wp[t * WS + k];
    Bp[k * 512 + 256 + t] = Wa[k * C + t];
}

// ---------------------------------------------------------------------------
// Kernel 1: f32 blocked GEMM  C[8192 x 512] = ct[8192 x 256] @ B[256 x 512].
// cols 0..255 -> h workspace (pre-tanh), cols 256..511 -> g.
// R4 lesson: need R2's FMA density AND >=4 waves/SIMD AND bounded weight
// traffic -> proper GEMM tiling. 64x64 tile, KC=64 LDS chunks (A transposed
// on write: 2-way bank alias only = free), thread tile 4x4 = 16 FMA per
// 2 ds_read_b128. 1024 blocks (4/CU), LDS 34.8KB/block (139KB/CU),
// __launch_bounds__(256,4) -> 4 waves/SIMD.
// ---------------------------------------------------------------------------
__global__ __launch_bounds__(256, 4) void precomp_gemm(const float* __restrict__ ct,
                                                       const float* __restrict__ Bp,
                                                       float* __restrict__ h,
                                                       float* __restrict__ g) {
    __shared__ __align__(16) float Al[KC][LDA];
    __shared__ __align__(16) float Bl[KC][LDA];

    const int t = threadIdx.x;
    const int bm = blockIdx.x >> 3;       // 0..127
    const int bn = blockIdx.x & 7;        // 0..7
    const int tm = t >> 4;                // 0..15  (output row group)
    const int tn = t & 15;                // 0..15  (output col group)
    const int sm = t >> 2;                // 0..63  (staging row)
    const int sf = t & 3;                 // 0..3   (staging float4 sub-col)

    const float4* ct4 = (const float4*)ct;   // [8192][64]
    const float4* B4  = (const float4*)Bp;   // [256][128]

    float acc[4][4] = {{0.f}};

    for (int kc = 0; kc < 256; kc += KC) {
        __syncthreads();
        // stage A (transpose [m][k] -> Al[k][m]); scalar writes, 2-way alias
#pragma unroll
        for (int i = 0; i < 4; i++) {
            const float4 a = ct4[(size_t)(bm * 64 + sm) * 64 + (kc >> 2) + sf + i * 4];
            const int kl = (sf + i * 4) * 4;
            Al[kl + 0][sm] = a.x;
            Al[kl + 1][sm] = a.y;
            Al[kl + 2][sm] = a.z;
            Al[kl + 3][sm] = a.w;
        }
        // stage B (same orientation, float4 writes)
#pragma unroll
        for (int i = 0; i < 4; i++) {
            const float4 b = B4[(size_t)(kc + sm) * 128 + bn * 16 + sf + i * 4];
            *(float4*)&Bl[sm][(sf + i * 4) * 4] = b;
        }
        __syncthreads();

#pragma unroll 8
        for (int kk = 0; kk < KC; kk++) {
            const float4 a = *(const float4*)&Al[kk][tm * 4];
            const float4 b = *(const float4*)&Bl[kk][tn * 4];
            acc[0][0] = fmaf(a.x, b.x, acc[0][0]);
            acc[0][1] = fmaf(a.x, b.y, acc[0][1]);
            acc[0][2] = fmaf(a.x, b.z, acc[0][2]);
            acc[0][3] = fmaf(a.x, b.w, acc[0][3]);
            acc[1][0] = fmaf(a.y, b.x, acc[1][0]);
            acc[1][1] = fmaf(a.y, b.y, acc[1][1]);
            acc[1][2] = fmaf(a.y, b.z, acc[1][2]);
            acc[1][3] = fmaf(a.y, b.w, acc[1][3]);
            acc[2][0] = fmaf(a.z, b.x, acc[2][0]);
            acc[2][1] = fmaf(a.z, b.y, acc[2][1]);
            acc[2][2] = fmaf(a.z, b.z, acc[2][2]);
            acc[2][3] = fmaf(a.z, b.w, acc[2][3]);
            acc[3][0] = fmaf(a.w, b.x, acc[3][0]);
            acc[3][1] = fmaf(a.w, b.y, acc[3][1]);
            acc[3][2] = fmaf(a.w, b.z, acc[3][2]);
            acc[3][3] = fmaf(a.w, b.w, acc[3][3]);
        }
    }

    // write: bn 0..3 -> h cols, bn 4..7 -> g cols. 16 consecutive tn lanes
    // store 256B contiguous per row -> coalesced.
    float* dst = (bn < 4) ? h : g;
    const int col = (bn < 4) ? (bn * 64 + tn * 4) : (bn * 64 + tn * 4 - 256);
#pragma unroll
    for (int i = 0; i < 4; i++) {
        const int row = bm * 64 + tm * 4 + i;
        *(float4*)&dst[(size_t)row * 256 + col] =
            make_float4(acc[i][0], acc[i][1], acc[i][2], acc[i][3]);
    }
}

// ---------------------------------------------------------------------------
// Kernel 2: p_t epilogue.  p_t[w] = S * sigmoid( sum_p tanh(h[w][p])*V_p[p] )
// ---------------------------------------------------------------------------
__global__ __launch_bounds__(256) void pt_kernel(const float* __restrict__ h,
                                                 const float* __restrict__ Vp,
                                                 float* __restrict__ pt) {
    __shared__ float red[16][4];
    const int t = threadIdx.x;
    const int lane = t & 63, wv = t >> 6;
    const int wbase = blockIdx.x * 16;
    const float vp = Vp[t];

#pragma unroll
    for (int r = 0; r < 16; r++) {
        float v = tanhf(h[(size_t)(wbase + r) * 256 + t]) * vp;
#pragma unroll
        for (int off = 32; off >= 1; off >>= 1) v += __shfl_xor(v, off);
        if (lane == 0) red[r][wv] = v;
    }
    __syncthreads();
    if (t < 16) {
        const float x = red[t][0] + red[t][1] + red[t][2] + red[t][3];
        const float sig = 1.f / (1.f + expf(-x));
        pt[wbase + t] = (float)S * sig;
    }
}

// ---------------------------------------------------------------------------
// Kernel 3: gather-attention, one wave per window (unchanged from R2).
// ---------------------------------------------------------------------------
__global__ __launch_bounds__(256) void attn(const float* __restrict__ q,
                                            const float* __restrict__ g,
                                            const float* __restrict__ pt,
                                            float* __restrict__ out) {
    const int tid = threadIdx.x;
    const int lane = tid & 63;
    const int wv = tid >> 6;
    const int wg = (blockIdx.x << 2) | wv;     // global window
    const int b = wg >> 11;                    // NW = 2048
    const int grp = lane >> 4;                 // key sub-slot
    const int sub = lane & 15;                 // channel group

    const float p = pt[wg];
    const int s0 = (int)p;                     // trunc == floor (p > 0)

    const float* grow = g + (size_t)wg * C + sub * 4;
    const float4 g0 = *(const float4*)(grow);
    const float4 g1 = *(const float4*)(grow + 64);
    const float4 g2 = *(const float4*)(grow + 128);
    const float4 g3 = *(const float4*)(grow + 192);

    const float* qb = q + (size_t)b * S * C + sub * 4;

    float m = -1e30f, den = 0.f;
    float4 a0 = {0, 0, 0, 0}, a1 = {0, 0, 0, 0}, a2 = {0, 0, 0, 0}, a3 = {0, 0, 0, 0};

    for (int it = 0; it < 17; it++) {
        const int k = it * 4 + grp;
        const int s = s0 + k - DD;
        const bool valid = (k <= 64) && ((unsigned)s < (unsigned)S);
        const int srow = min(max(s, 0), S - 1);

        const float* qr = qb + (size_t)srow * C;
        const float4 q0 = *(const float4*)(qr);
        const float4 q1 = *(const float4*)(qr + 64);
        const float4 q2 = *(const float4*)(qr + 128);
        const float4 q3 = *(const float4*)(qr + 192);

        float d = q0.x * g0.x;
        d = fmaf(q0.y, g0.y, d); d = fmaf(q0.z, g0.z, d); d = fmaf(q0.w, g0.w, d);
        d = fmaf(q1.x, g1.x, d); d = fmaf(q1.y, g1.y, d);
        d = fmaf(q1.z, g1.z, d); d = fmaf(q1.w, g1.w, d);
        d = fmaf(q2.x, g2.x, d); d = fmaf(q2.y, g2.y, d);
        d = fmaf(q2.z, g2.z, d); d = fmaf(q2.w, g2.w, d);
        d = fmaf(q3.x, g3.x, d); d = fmaf(q3.y, g3.y, d);
        d = fmaf(q3.z, g3.z, d); d = fmaf(q3.w, g3.w, d);
#pragma unroll
        for (int off = 8; off >= 1; off >>= 1) d += __shfl_xor(d, off);

        d = valid ? d : -3e38f;

        const float fs = (float)s - p;
        const float tt = fs * (1.f / (float)DD);
        const float lg = -2.f * tt * tt;

        const float mn = fmaxf(m, d);
        const float sc = __expf(m - mn);       // rescale old state
        const float e  = __expf(d - mn);       // denominator term
        const float eg = __expf(d - mn + lg);  // numerator term (exp * gauss)
        den = fmaf(den, sc, e);
        m = mn;

        a0.x = fmaf(eg, q0.x, a0.x * sc); a0.y = fmaf(eg, q0.y, a0.y * sc);
        a0.z = fmaf(eg, q0.z, a0.z * sc); a0.w = fmaf(eg, q0.w, a0.w * sc);
        a1.x = fmaf(eg, q1.x, a1.x * sc); a1.y = fmaf(eg, q1.y, a1.y * sc);
        a1.z = fmaf(eg, q1.z, a1.z * sc); a1.w = fmaf(eg, q1.w, a1.w * sc);
        a2.x = fmaf(eg, q2.x, a2.x * sc); a2.y = fmaf(eg, q2.y, a2.y * sc);
        a2.z = fmaf(eg, q2.z, a2.z * sc); a2.w = fmaf(eg, q2.w, a2.w * sc);
        a3.x = fmaf(eg, q3.x, a3.x * sc); a3.y = fmaf(eg, q3.y, a3.y * sc);
        a3.z = fmaf(eg, q3.z, a3.z * sc); a3.w = fmaf(eg, q3.w, a3.w * sc);
    }

    // merge the 4 groups (cross-lane butterfly; m/den uniform within group)
    float M = m;
    M = fmaxf(M, __shfl_xor(M, 16));
    M = fmaxf(M, __shfl_xor(M, 32));
    const float scg = __expf(m - M);

    den *= scg;
    den += __shfl_xor(den, 16);
    den += __shfl_xor(den, 32);

#define MERGE(v) { v *= scg; v += __shfl_xor(v, 16); v += __shfl_xor(v, 32); }
    MERGE(a0.x) MERGE(a0.y) MERGE(a0.z) MERGE(a0.w)
    MERGE(a1.x) MERGE(a1.y) MERGE(a1.z) MERGE(a1.w)
    MERGE(a2.x) MERGE(a2.y) MERGE(a2.z) MERGE(a2.w)
    MERGE(a3.x) MERGE(a3.y) MERGE(a3.z) MERGE(a3.w)
#undef MERGE

    float4 o = a0;
    if (grp == 1) o = a1;
    else if (grp == 2) o = a2;
    else if (grp == 3) o = a3;

    const float r = 1.f / den;
    o.x *= r; o.y *= r; o.z *= r; o.w *= r;

    *(float4*)(out + (size_t)wg * C + lane * 4) = o;
}

// ---------------------------------------------------------------------------
extern "C" void kernel_launch(void* const* d_in, const int* in_sizes, int n_in,
                              void* d_out, int out_size, void* d_ws, size_t ws_size,
                              hipStream_t stream) {
    const float* q  = (const float*)d_in[0];
    const float* ct = (const float*)d_in[1];
    const float* Wa = (const float*)d_in[2];
    const float* Wp = (const float*)d_in[3];
    const float* Vp = (const float*)d_in[4];
    float* out = (float*)d_out;

    char* ws = (char*)d_ws;
    float* Bp = (float*)ws;                             // 512 KB
    float* pt = (float*)(ws + 524288);                  // 32 KB
    float* h  = (float*)(ws + 524288 + 32768);          // 8 MB
    float* g  = (float*)(ws + 524288 + 32768 + 8388608);// 8 MB
    // total ~16.9 MB workspace

    prep_B<<<256, 256, 0, stream>>>(Wp, Wa, Bp);
    precomp_gemm<<<1024, 256, 0, stream>>>(ct, Bp, h, g);
    pt_kernel<<<TOTW / 16, 256, 0, stream>>>(h, Vp, pt);
    attn<<<TOTW / 4, 256, 0, stream>>>(q, g, pt, out);
}

// Round 6
// 83.422 us; speedup vs baseline: 1.8860x; 1.2699x over previous
//
#include <hip/hip_runtime.h>
#include <math.h>

#define BB 4
#define S 8192
#define C 256
#define NW 2048
#define WS 256
#define PSZ 256
#define DD 32
#define KK 65
#define TOTW (BB * NW) /* 8192 */

#define KC 64
#define LDA 68  /* 64 + 4 pad, keeps 16B alignment (68*4=272=17*16) */
#define NBKT 64                 /* position buckets per batch (128 rows each) */
#define TBKT (BB * NBKT)        /* 256 total buckets */

// ---------------------------------------------------------------------------
// Kernel 0: pack B [256 k][512 cols] = [ Wp^T | Wa ]; block 0 zeroes the
// bucket counters (stream-ordered before the histogram).
// ---------------------------------------------------------------------------
__global__ __launch_bounds__(256) void prep_B(const float* __restrict__ Wp,
                                              const float* __restrict__ Wa,
                                              float* __restrict__ Bp,
                                              int* __restrict__ cnt) {
    const int k = blockIdx.x;
    const int t = threadIdx.x;
    Bp[k * 512 + t] = Wp[t * WS + k];
    Bp[k * 512 + 256 + t] = Wa[k * C + t];
    if (k == 0) cnt[t] = 0;
}

// ---------------------------------------------------------------------------
// Kernel 1: f32 blocked GEMM  C[8192 x 512] = ct[8192 x 256] @ B[256 x 512].
// bn 4..7 -> g. bn 0..3 (h cols): do NOT materialize h — fuse the p_t
// partial reduction: ptpart[row][bn] = sum_{cols of this block} tanh(h)*Vp.
// Deterministic (fixed 4-partial layout, no atomics).
// ---------------------------------------------------------------------------
__global__ __launch_bounds__(256, 4) void precomp_gemm(const float* __restrict__ ct,
                                                       const float* __restrict__ Bp,
                                                       const float* __restrict__ Vp,
                                                       float* __restrict__ ptpart,
                                                       float* __restrict__ g) {
    __shared__ __align__(16) float Al[KC][LDA];
    __shared__ __align__(16) float Bl[KC][LDA];

    const int t = threadIdx.x;
    const int bm = blockIdx.x >> 3;       // 0..127
    const int bn = blockIdx.x & 7;        // 0..7
    const int tm = t >> 4;                // 0..15
    const int tn = t & 15;                // 0..15
    const int sm = t >> 2;                // 0..63
    const int sf = t & 3;                 // 0..3

    const float4* ct4 = (const float4*)ct;   // [8192][64]
    const float4* B4  = (const float4*)Bp;   // [256][128]

    float acc[4][4] = {{0.f}};

    for (int kc = 0; kc < 256; kc += KC) {
        __syncthreads();
#pragma unroll
        for (int i = 0; i < 4; i++) {
            const float4 a = ct4[(size_t)(bm * 64 + sm) * 64 + (kc >> 2) + sf + i * 4];
            const int kl = (sf + i * 4) * 4;
            Al[kl + 0][sm] = a.x;
            Al[kl + 1][sm] = a.y;
            Al[kl + 2][sm] = a.z;
            Al[kl + 3][sm] = a.w;
        }
#pragma unroll
        for (int i = 0; i < 4; i++) {
            const float4 b = B4[(size_t)(kc + sm) * 128 + bn * 16 + sf + i * 4];
            *(float4*)&Bl[sm][(sf + i * 4) * 4] = b;
        }
        __syncthreads();

#pragma unroll 8
        for (int kk = 0; kk < KC; kk++) {
            const float4 a = *(const float4*)&Al[kk][tm * 4];
            const float4 b = *(const float4*)&Bl[kk][tn * 4];
            acc[0][0] = fmaf(a.x, b.x, acc[0][0]);
            acc[0][1] = fmaf(a.x, b.y, acc[0][1]);
            acc[0][2] = fmaf(a.x, b.z, acc[0][2]);
            acc[0][3] = fmaf(a.x, b.w, acc[0][3]);
            acc[1][0] = fmaf(a.y, b.x, acc[1][0]);
            acc[1][1] = fmaf(a.y, b.y, acc[1][1]);
            acc[1][2] = fmaf(a.y, b.z, acc[1][2]);
            acc[1][3] = fmaf(a.y, b.w, acc[1][3]);
            acc[2][0] = fmaf(a.z, b.x, acc[2][0]);
            acc[2][1] = fmaf(a.z, b.y, acc[2][1]);
            acc[2][2] = fmaf(a.z, b.z, acc[2][2]);
            acc[2][3] = fmaf(a.z, b.w, acc[2][3]);
            acc[3][0] = fmaf(a.w, b.x, acc[3][0]);
            acc[3][1] = fmaf(a.w, b.y, acc[3][1]);
            acc[3][2] = fmaf(a.w, b.z, acc[3][2]);
            acc[3][3] = fmaf(a.w, b.w, acc[3][3]);
        }
    }

    if (bn >= 4) {
        // g columns: coalesced float4 stores
        const int col = bn * 64 + tn * 4 - 256;
#pragma unroll
        for (int i = 0; i < 4; i++) {
            const int row = bm * 64 + tm * 4 + i;
            *(float4*)&g[(size_t)row * 256 + col] =
                make_float4(acc[i][0], acc[i][1], acc[i][2], acc[i][3]);
        }
    } else {
        // h columns: fused p_t partial. col = bn*64 + tn*4 + j.
        const float4 vp4 = ((const float4*)Vp)[bn * 16 + tn];
#pragma unroll
        for (int i = 0; i < 4; i++) {
            float v = tanhf(acc[i][0]) * vp4.x;
            v = fmaf(tanhf(acc[i][1]), vp4.y, v);
            v = fmaf(tanhf(acc[i][2]), vp4.z, v);
            v = fmaf(tanhf(acc[i][3]), vp4.w, v);
            // reduce across tn (16 consecutive lanes share tm)
#pragma unroll
            for (int off = 8; off >= 1; off >>= 1) v += __shfl_xor(v, off);
            if (tn == 0) {
                const int row = bm * 64 + tm * 4 + i;
                ptpart[row * 4 + bn] = v;
            }
        }
    }
}

// ---------------------------------------------------------------------------
// Kernel 2: finalize p_t + position histogram.
// ---------------------------------------------------------------------------
__global__ __launch_bounds__(256) void pt_hist(const float* __restrict__ ptpart,
                                               float* __restrict__ pt,
                                               int* __restrict__ cnt) {
    const int wg = blockIdx.x * 256 + threadIdx.x;
    const float4 pp = ((const float4*)ptpart)[wg];
    const float x = (pp.x + pp.y) + (pp.z + pp.w);
    const float p = (float)S / (1.f + expf(-x));
    pt[wg] = p;
    const int s0 = (int)p;
    const int bkt = (wg >> 11) * NBKT + min(NBKT - 1, max(0, s0 >> 7));
    atomicAdd(&cnt[bkt], 1);
}

// ---------------------------------------------------------------------------
// Kernel 3: exclusive scan of 256 bucket counts -> scatter cursors.
// ---------------------------------------------------------------------------
__global__ __launch_bounds__(256) void scan_kernel(const int* __restrict__ cnt,
                                                   int* __restrict__ offs) {
    __shared__ int sh[TBKT];
    const int t = threadIdx.x;
    const int v = cnt[t];
    sh[t] = v;
    __syncthreads();
    for (int d = 1; d < TBKT; d <<= 1) {
        const int x = (t >= d) ? sh[t - d] : 0;
        __syncthreads();
        sh[t] += x;
        __syncthreads();
    }
    offs[t] = sh[t] - v;   // exclusive
}

// ---------------------------------------------------------------------------
// Kernel 4: scatter window ids into position-sorted permutation.
// Within-bucket order is nondeterministic (atomic cursor) but each window's
// output is independent of processing order -> results deterministic.
// ---------------------------------------------------------------------------
__global__ __launch_bounds__(256) void scatter_kernel(const float* __restrict__ pt,
                                                      int* __restrict__ offs,
                                                      int* __restrict__ perm) {
    const int wg = blockIdx.x * 256 + threadIdx.x;
    const int s0 = (int)pt[wg];
    const int bkt = (wg >> 11) * NBKT + min(NBKT - 1, max(0, s0 >> 7));
    const int pos = atomicAdd(&offs[bkt], 1);
    perm[pos] = wg;
}

// ---------------------------------------------------------------------------
// Kernel 5: gather-attention (compute identical to R2). Windows consumed in
// position-sorted order via perm[]; XCD-chunked swizzle keeps each XCD's
// gather footprint a ~1-2 MB contiguous q span (L2-resident).
// ---------------------------------------------------------------------------
__global__ __launch_bounds__(256) void attn(const float* __restrict__ q,
                                            const float* __restrict__ g,
                                            const float* __restrict__ pt,
                                            const int* __restrict__ perm,
                                            float* __restrict__ out) {
    const int tid = threadIdx.x;
    const int lane = tid & 63;
    const int wv = tid >> 6;
    const int bid = blockIdx.x;
    // 2048 blocks round-robin XCDs by bid&7 -> give each XCD a contiguous
    // 256-block chunk of the sorted list
    const int sb = (bid & 7) * 256 + (bid >> 3);
    const int wg = perm[sb * 4 + wv];
    const int b = wg >> 11;                    // NW = 2048
    const int grp = lane >> 4;                 // key sub-slot
    const int sub = lane & 15;                 // channel group

    const float p = pt[wg];
    const int s0 = (int)p;                     // trunc == floor (p > 0)

    const float* grow = g + (size_t)wg * C + sub * 4;
    const float4 g0 = *(const float4*)(grow);
    const float4 g1 = *(const float4*)(grow + 64);
    const float4 g2 = *(const float4*)(grow + 128);
    const float4 g3 = *(const float4*)(grow + 192);

    const float* qb = q + (size_t)b * S * C + sub * 4;

    float m = -1e30f, den = 0.f;
    float4 a0 = {0, 0, 0, 0}, a1 = {0, 0, 0, 0}, a2 = {0, 0, 0, 0}, a3 = {0, 0, 0, 0};

    for (int it = 0; it < 17; it++) {
        const int k = it * 4 + grp;
        const int s = s0 + k - DD;
        const bool valid = (k <= 64) && ((unsigned)s < (unsigned)S);
        const int srow = min(max(s, 0), S - 1);

        const float* qr = qb + (size_t)srow * C;
        const float4 q0 = *(const float4*)(qr);
        const float4 q1 = *(const float4*)(qr + 64);
        const float4 q2 = *(const float4*)(qr + 128);
        const float4 q3 = *(const float4*)(qr + 192);

        float d = q0.x * g0.x;
        d = fmaf(q0.y, g0.y, d); d = fmaf(q0.z, g0.z, d); d = fmaf(q0.w, g0.w, d);
        d = fmaf(q1.x, g1.x, d); d = fmaf(q1.y, g1.y, d);
        d = fmaf(q1.z, g1.z, d); d = fmaf(q1.w, g1.w, d);
        d = fmaf(q2.x, g2.x, d); d = fmaf(q2.y, g2.y, d);
        d = fmaf(q2.z, g2.z, d); d = fmaf(q2.w, g2.w, d);
        d = fmaf(q3.x, g3.x, d); d = fmaf(q3.y, g3.y, d);
        d = fmaf(q3.z, g3.z, d); d = fmaf(q3.w, g3.w, d);
#pragma unroll
        for (int off = 8; off >= 1; off >>= 1) d += __shfl_xor(d, off);

        d = valid ? d : -3e38f;

        const float fs = (float)s - p;
        const float tt = fs * (1.f / (float)DD);
        const float lg = -2.f * tt * tt;

        const float mn = fmaxf(m, d);
        const float sc = __expf(m - mn);       // rescale old state
        const float e  = __expf(d - mn);       // denominator term
        const float eg = __expf(d - mn + lg);  // numerator term (exp * gauss)
        den = fmaf(den, sc, e);
        m = mn;

        a0.x = fmaf(eg, q0.x, a0.x * sc); a0.y = fmaf(eg, q0.y, a0.y * sc);
        a0.z = fmaf(eg, q0.z, a0.z * sc); a0.w = fmaf(eg, q0.w, a0.w * sc);
        a1.x = fmaf(eg, q1.x, a1.x * sc); a1.y = fmaf(eg, q1.y, a1.y * sc);
        a1.z = fmaf(eg, q1.z, a1.z * sc); a1.w = fmaf(eg, q1.w, a1.w * sc);
        a2.x = fmaf(eg, q2.x, a2.x * sc); a2.y = fmaf(eg, q2.y, a2.y * sc);
        a2.z = fmaf(eg, q2.z, a2.z * sc); a2.w = fmaf(eg, q2.w, a2.w * sc);
        a3.x = fmaf(eg, q3.x, a3.x * sc); a3.y = fmaf(eg, q3.y, a3.y * sc);
        a3.z = fmaf(eg, q3.z, a3.z * sc); a3.w = fmaf(eg, q3.w, a3.w * sc);
    }

    // merge the 4 groups (cross-lane butterfly; m/den uniform within group)
    float M = m;
    M = fmaxf(M, __shfl_xor(M, 16));
    M = fmaxf(M, __shfl_xor(M, 32));
    const float scg = __expf(m - M);

    den *= scg;
    den += __shfl_xor(den, 16);
    den += __shfl_xor(den, 32);

#define MERGE(v) { v *= scg; v += __shfl_xor(v, 16); v += __shfl_xor(v, 32); }
    MERGE(a0.x) MERGE(a0.y) MERGE(a0.z) MERGE(a0.w)
    MERGE(a1.x) MERGE(a1.y) MERGE(a1.z) MERGE(a1.w)
    MERGE(a2.x) MERGE(a2.y) MERGE(a2.z) MERGE(a2.w)
    MERGE(a3.x) MERGE(a3.y) MERGE(a3.z) MERGE(a3.w)
#undef MERGE

    float4 o = a0;
    if (grp == 1) o = a1;
    else if (grp == 2) o = a2;
    else if (grp == 3) o = a3;

    const float r = 1.f / den;
    o.x *= r; o.y *= r; o.z *= r; o.w *= r;

    *(float4*)(out + (size_t)wg * C + lane * 4) = o;
}

// ---------------------------------------------------------------------------
extern "C" void kernel_launch(void* const* d_in, const int* in_sizes, int n_in,
                              void* d_out, int out_size, void* d_ws, size_t ws_size,
                              hipStream_t stream) {
    const float* q  = (const float*)d_in[0];
    const float* ct = (const float*)d_in[1];
    const float* Wa = (const float*)d_in[2];
    const float* Wp = (const float*)d_in[3];
    const float* Vp = (const float*)d_in[4];
    float* out = (float*)d_out;

    char* ws = (char*)d_ws;
    float* Bp     = (float*)ws;                   // 512 KB
    float* ptpart = (float*)(ws + 524288);        // 128 KB
    float* pt     = (float*)(ws + 655360);        // 32 KB
    int*   cnt    = (int*)  (ws + 688128);        // 1 KB
    int*   offs   = (int*)  (ws + 689152);        // 1 KB
    int*   perm   = (int*)  (ws + 690176);        // 32 KB
    float* g      = (float*)(ws + 722944);        // 8 MB
    // total ~9.1 MB workspace

    prep_B<<<256, 256, 0, stream>>>(Wp, Wa, Bp, cnt);
    precomp_gemm<<<1024, 256, 0, stream>>>(ct, Bp, Vp, ptpart, g);
    pt_hist<<<TOTW / 256, 256, 0, stream>>>(ptpart, pt, cnt);
    scan_kernel<<<1, TBKT, 0, stream>>>(cnt, offs);
    scatter_kernel<<<TOTW / 256, 256, 0, stream>>>(pt, offs, perm);
    attn<<<TOTW / 4, 256, 0, stream>>>(q, g, pt, perm, out);
}